// Round 9
// baseline (310.362 us; speedup 1.0000x reference)
//
#include <hip/hip_runtime.h>

// HMULayer omega: out[b][n] = exp(-(lam_n*||x_b-mu_n||^2 + sum_k om_nk*((x_b-mu_n).v_nk)^2)/D)
// B=1024, N=8192, D=256, K=8. 9 fused bf16 MFMA GEMMs sharing A=x.
// R13: WEIGHTS-STATIONARY main. Corrected model vs R4-R12: LDS/L2/staging all
//      far from their pipes' limits; MfmaUtil pinned at 25-29% across every
//      structure => single-wave MFMA issue can't fill the pipe and reg pressure
//      (144-AGPR acc) blocks TLP. Fix by swapping MFMA operand roles:
//  - W-tile (16n x <=3j x K=256) lives in REGISTERS per wave (<=96 VGPR),
//    loaded once from pw. A-operand.
//  - x-fragments stream from L2/L1 as B-operand (px 512KB, L2-resident;
//    same lane layout as A-frags - verified pattern from R9).
//  - ZERO LDS reads, ZERO staging, ZERO barriers in the K-loop. acc = 12 AGPR.
//    ~160 regs -> 3 waves/SIMD, phases uncorrelated.
//  - j-split across 4 waves {3,2,2,2}, rotated by blockIdx for SIMD balance;
//    partials combined per 4 b-tiles via 16KB LDS scratch (2 barriers/4 tiles).
//  - D-layout here: row=n (kg*4+r), col=b (lane&15).

#define B_SZ 1024
#define N_SZ 8192
#define D_SZ 256
#define K_SZ 8

#define BT 128       // fallback b-tile
#define NT 16

typedef __bf16 bf16x8 __attribute__((ext_vector_type(8)));
typedef float f32x4 __attribute__((ext_vector_type(4)));
typedef unsigned short u16x4 __attribute__((ext_vector_type(4)));
typedef unsigned short u16x8 __attribute__((ext_vector_type(8)));

// ws byte offsets (R4 layout)
#define WS_X2   0u          // f32[1024]
#define WS_MU2  4096u       // f32[8192]
#define WS_MUV  36864u      // f32[65536]
#define WS_PX   299008u     // bf16[1024*256]   (512 KB)
#define WS_PW   823296u     // bf16[8192*9*256] (36 MB)
#define WS_NEED (823296ull + 37748736ull)

__device__ __forceinline__ float wave_reduce(float s) {
#pragma unroll
  for (int off = 32; off > 0; off >>= 1) s += __shfl_down(s, off);
  return s;
}

__device__ __forceinline__ u16x4 cvt4(float4 t) {
  u16x4 r;
  r[0] = __builtin_bit_cast(unsigned short, (__bf16)t.x);
  r[1] = __builtin_bit_cast(unsigned short, (__bf16)t.y);
  r[2] = __builtin_bit_cast(unsigned short, (__bf16)t.z);
  r[3] = __builtin_bit_cast(unsigned short, (__bf16)t.w);
  return r;
}

// ---- prep_all v2: one wave per row. g<1024: x-row. g<9216: mu-row. else v-row.
__global__ void prep_all(const float* __restrict__ x, const float* __restrict__ mu,
                         const float* __restrict__ v,
                         float* __restrict__ x2, unsigned short* __restrict__ px,
                         float* __restrict__ mu2, float* __restrict__ muv,
                         unsigned short* __restrict__ pw) {
  const int w = threadIdx.x >> 6, lane = threadIdx.x & 63;
  const int g = blockIdx.x * 4 + w;
  if (g < B_SZ) {
    const int b = g;
    float4 t = *(const float4*)(x + (size_t)b * D_SZ + 4 * lane);
    *(u16x4*)(px + (size_t)b * D_SZ + 4 * lane) = cvt4(t);
    float s = t.x * t.x + t.y * t.y + t.z * t.z + t.w * t.w;
    s = wave_reduce(s);
    if (lane == 0) x2[b] = s;
  } else if (g < B_SZ + N_SZ) {
    const int n = g - B_SZ;
    float4 m4 = *(const float4*)(mu + (size_t)n * D_SZ + 4 * lane);
    *(u16x4*)(pw + (size_t)n * 9 * D_SZ + 4 * lane) = cvt4(m4);
    float s = m4.x * m4.x + m4.y * m4.y + m4.z * m4.z + m4.w * m4.w;
    s = wave_reduce(s);
    if (lane == 0) mu2[n] = s;
  } else {
    const int idx = g - (B_SZ + N_SZ);
    const int n = idx >> 3, k = idx & 7;
    float4 m4 = *(const float4*)(mu + (size_t)n * D_SZ + 4 * lane);
    float4 v4 = *(const float4*)(v + ((size_t)n * K_SZ + k) * D_SZ + 4 * lane);
    *(u16x4*)(pw + ((size_t)n * 9 + k + 1) * D_SZ + 4 * lane) = cvt4(v4);
    float s = m4.x * v4.x + m4.y * v4.y + m4.z * v4.z + m4.w * v4.w;
    s = wave_reduce(s);
    if (lane == 0) muv[n * K_SZ + k] = s;
  }
}

// ---- main: weights-stationary, register-resident W, streamed x ----
__global__ __launch_bounds__(256, 2)
void hmu_ws(const unsigned short* __restrict__ px,
            const unsigned short* __restrict__ pw,
            const float* __restrict__ lam, const float* __restrict__ om,
            const float* __restrict__ wsf, float* __restrict__ out) {
  // scratch: [tile(4)][slot(4)][b(16)][n(16)] f32 = 16 KB
  __shared__ __align__(16) float scr[4 * 4 * 16 * 16];

  const float* ws_x2 = wsf;                    // WS_X2/4
  const float* ws_mu2 = wsf + 1024;            // WS_MU2/4
  const float* ws_muv = wsf + 9216;            // WS_MUV/4

  const int tid = threadIdx.x;
  const int lane = tid & 63;
  const int w = tid >> 6;
  const int c = lane & 15;          // fragment column -> b within tile
  const int kg = lane >> 4;         // k-subslice / n-quad selector

  // XCD-chunked decode, b-half innermost (pw lines shared by adjacent blocks)
  const int bid = blockIdx.x;
  const int xcd = bid & 7;
  const int idx = bid >> 3;                       // 0..127
  const int n0 = (xcd * 64 + (idx >> 1)) * NT;    // n-tile
  const int bs = idx & 1;                          // b half: rows bs*512..+511

  // j-set rotation across blocks for SIMD load balance.
  const int wsel = (w + bid) & 3;
  const int jbase = (wsel == 0) ? 0 : (2 * wsel + 1);   // 0,3,5,7
  const int jcnt = (wsel == 0) ? 3 : 2;                 // {3,2,2,2}

  // ---- per-lane n-scalars: n_r = n0 + kg*4 + r ----
  // wsel==0: acc[0]=c0 (j=0), acc[1]/acc[2] <-> k-pair {0,1}
  // wsel>0 : acc[0]/acc[1] <-> k-pair {2wsel, 2wsel+1}
  const int kpair = (wsel == 0) ? 0 : 2 * wsel;
  float lamr[4], lm2r[4], omA[4], omB[4], muvA[4], muvB[4];
#pragma unroll
  for (int r = 0; r < 4; ++r) {
    int n_r = n0 + kg * 4 + r;
    if (wsel == 0) {
      lamr[r] = lam[n_r];
      lm2r[r] = ws_mu2[n_r];
    }
    omA[r] = om[n_r * 8 + kpair];
    omB[r] = om[n_r * 8 + kpair + 1];
    muvA[r] = ws_muv[n_r * 8 + kpair];
    muvB[r] = ws_muv[n_r * 8 + kpair + 1];
  }

  // ---- W fragments (A-operand), register-resident for the whole kernel:
  // lane (kg,c): pw[n0+c][jbase+jj][kt*32 + kg*8 .. +8]
  bf16x8 wf[3][8];
#pragma unroll
  for (int jj = 0; jj < 3; ++jj) {
    if (jj < jcnt) {
#pragma unroll
      for (int kt = 0; kt < 8; ++kt)
        wf[jj][kt] = *(const bf16x8*)(
            pw + ((size_t)(n0 + c) * 9 + (jbase + jj)) * D_SZ + kt * 32 + kg * 8);
    }
  }

  const unsigned short* pxb = px + (size_t)(bs * 512 + c) * D_SZ + kg * 8;

  for (int g = 0; g < 8; ++g) {
#pragma unroll
    for (int t = 0; t < 4; ++t) {
      const int tile = g * 4 + t;
      const unsigned short* pxt = pxb + (size_t)tile * 16 * D_SZ;

      f32x4 acc0 = (f32x4){0.f, 0.f, 0.f, 0.f};
      f32x4 acc1 = (f32x4){0.f, 0.f, 0.f, 0.f};
      f32x4 acc2 = (f32x4){0.f, 0.f, 0.f, 0.f};

      // B-operand x-frags streamed from L1/L2, 2-deep rolling prefetch
      bf16x8 xf[2];
      xf[0] = *(const bf16x8*)(pxt);
      xf[1] = *(const bf16x8*)(pxt + 32);
#pragma unroll
      for (int kt = 0; kt < 8; ++kt) {
        bf16x8 xc = xf[kt & 1];
        if (kt < 6) xf[kt & 1] = *(const bf16x8*)(pxt + (kt + 2) * 32);
        acc0 = __builtin_amdgcn_mfma_f32_16x16x32_bf16(wf[0][kt], xc, acc0, 0, 0, 0);
        acc1 = __builtin_amdgcn_mfma_f32_16x16x32_bf16(wf[1][kt], xc, acc1, 0, 0, 0);
        if (wsel == 0)
          acc2 = __builtin_amdgcn_mfma_f32_16x16x32_bf16(wf[2][kt], xc, acc2, 0, 0, 0);
      }

      // partial q for this wave's j-set; D-layout: row n=kg*4+r, col b=c
      f32x4 qv;
      if (wsel == 0) {
        float x2b = ws_x2[bs * 512 + tile * 16 + c];
#pragma unroll
        for (int r = 0; r < 4; ++r) {
          float q = lamr[r] * (x2b - 2.f * acc0[r] + lm2r[r]);
          float pA = acc1[r] - muvA[r];
          q = fmaf(omA[r] * pA, pA, q);
          float pB = acc2[r] - muvB[r];
          qv[r] = fmaf(omB[r] * pB, pB, q);
        }
      } else {
#pragma unroll
        for (int r = 0; r < 4; ++r) {
          float pA = acc0[r] - muvA[r];
          float q = omA[r] * pA * pA;
          float pB = acc1[r] - muvB[r];
          qv[r] = fmaf(omB[r] * pB, pB, q);
        }
      }
      *(f32x4*)&scr[((t * 4 + wsel) * 16 + c) * 16 + kg * 4] = qv;
    }
    __syncthreads();

    // combine: wave w finishes tile g*4+w (sum 4 slots, exp, store)
    {
      f32x4 s0 = *(const f32x4*)&scr[((w * 4 + 0) * 16 + c) * 16 + kg * 4];
      f32x4 s1 = *(const f32x4*)&scr[((w * 4 + 1) * 16 + c) * 16 + kg * 4];
      f32x4 s2 = *(const f32x4*)&scr[((w * 4 + 2) * 16 + c) * 16 + kg * 4];
      f32x4 s3 = *(const f32x4*)&scr[((w * 4 + 3) * 16 + c) * 16 + kg * 4];
      f32x4 o;
#pragma unroll
      for (int r = 0; r < 4; ++r) {
        float q = (s0[r] + s1[r]) + (s2[r] + s3[r]);
        o[r] = __expf(q * (-1.0f / 256.0f));
      }
      *(f32x4*)(out + (size_t)(bs * 512 + (g * 4 + w) * 16 + c) * N_SZ + n0 + kg * 4) = o;
    }
    __syncthreads();
  }
}

// ================= fallback path (R2): in-loop cvt staging =================
__device__ __forceinline__ void cvt16_store(const float* __restrict__ src,
                                            unsigned short* dst) {
  const float4* p4 = (const float4*)src;
  float fv[16];
#pragma unroll
  for (int e = 0; e < 4; ++e) {
    float4 t = p4[e];
    fv[4 * e + 0] = t.x; fv[4 * e + 1] = t.y;
    fv[4 * e + 2] = t.z; fv[4 * e + 3] = t.w;
  }
  u16x8 lo, hi;
#pragma unroll
  for (int e = 0; e < 8; ++e) {
    lo[e] = __builtin_bit_cast(unsigned short, (__bf16)fv[e]);
    hi[e] = __builtin_bit_cast(unsigned short, (__bf16)fv[e + 8]);
  }
  *(u16x8*)dst = lo;
  *(u16x8*)(dst + 8) = hi;
}

#define LDS_STRIDE 40
__global__ __launch_bounds__(256, 2)
void hmu_main_f(const float* __restrict__ x, const float* __restrict__ mu,
                const float* __restrict__ lam, const float* __restrict__ v,
                const float* __restrict__ om, const float* __restrict__ ws,
                float* __restrict__ out) {
  __shared__ __align__(16) unsigned short As[BT * LDS_STRIDE];
  __shared__ __align__(16) unsigned short Bs[NT * 9 * LDS_STRIDE];
  const float* ws_x2 = ws;
  const float* ws_mu2 = ws + 1024;
  const float* ws_muv = ws + 9216;
  const int tid = threadIdx.x, lane = tid & 63, w = tid >> 6;
  const int m = lane & 15, kg = lane >> 4;
  const int n0 = blockIdx.x * NT, b0 = blockIdx.y * BT;
  f32x4 acc[2][9];
#pragma unroll
  for (int bs = 0; bs < 2; ++bs)
#pragma unroll
    for (int j = 0; j < 9; ++j) acc[bs][j] = (f32x4){0.f, 0.f, 0.f, 0.f};
  const int arow = tid >> 1, ahalf = tid & 1;
  for (int kt = 0; kt < 8; ++kt) {
    const int k0 = kt * 32;
    cvt16_store(x + (size_t)(b0 + arow) * D_SZ + k0 + ahalf * 16,
                &As[arow * LDS_STRIDE + ahalf * 16]);
#pragma unroll
    for (int it = 0; it < 2; ++it) {
      int idx = tid + 256 * it;
      if (idx < 288) {
        int row = idx >> 1, half = idx & 1;
        int nl = row / 9, j = row - nl * 9;
        const float* src = (j == 0)
            ? mu + (size_t)(n0 + nl) * D_SZ + k0 + half * 16
            : v + (size_t)((n0 + nl) * K_SZ + (j - 1)) * D_SZ + k0 + half * 16;
        cvt16_store(src, &Bs[row * LDS_STRIDE + half * 16]);
      }
    }
    __syncthreads();
    bf16x8 af[2];
#pragma unroll
    for (int bs = 0; bs < 2; ++bs)
      af[bs] = *(const bf16x8*)&As[((2 * w + bs) * 16 + m) * LDS_STRIDE + kg * 8];
#pragma unroll
    for (int j = 0; j < 9; ++j) {
      bf16x8 bfr = *(const bf16x8*)&Bs[(m * 9 + j) * LDS_STRIDE + kg * 8];
      acc[0][j] = __builtin_amdgcn_mfma_f32_16x16x32_bf16(af[0], bfr, acc[0][j], 0, 0, 0);
      acc[1][j] = __builtin_amdgcn_mfma_f32_16x16x32_bf16(af[1], bfr, acc[1][j], 0, 0, 0);
    }
    __syncthreads();
  }
  const int n = n0 + m;
  const float lam_n = lam[n];
  const float mu2_n = ws_mu2[n];
  float omr[8], muvr[8];
#pragma unroll
  for (int k = 0; k < 8; ++k) {
    omr[k] = om[n * 8 + k];
    muvr[k] = ws_muv[n * 8 + k];
  }
#pragma unroll
  for (int bs = 0; bs < 2; ++bs)
#pragma unroll
    for (int r = 0; r < 4; ++r) {
      int b = b0 + (2 * w + bs) * 16 + kg * 4 + r;
      float c0 = acc[bs][0][r];
      float q = lam_n * (ws_x2[b] - 2.f * c0 + mu2_n);
#pragma unroll
      for (int k = 0; k < 8; ++k) {
        float p = acc[bs][k + 1][r] - muvr[k];
        q = fmaf(omr[k] * p, p, q);
      }
      out[(size_t)b * N_SZ + n] = __expf(q * (-1.0f / 256.0f));
    }
}

__global__ void p2_mu_f(const float* __restrict__ mu, const float* __restrict__ v,
                        float* __restrict__ mu2, float* __restrict__ muv) {
  __shared__ __align__(16) float mulds[D_SZ];
  const int n = blockIdx.x;
  const int w = threadIdx.x >> 6, lane = threadIdx.x & 63;
  if (w == 0) {
    float4 m4 = *(const float4*)(mu + (size_t)n * D_SZ + 4 * lane);
    *(float4*)(mulds + 4 * lane) = m4;
    float s = m4.x * m4.x + m4.y * m4.y + m4.z * m4.z + m4.w * m4.w;
    s = wave_reduce(s);
    if (lane == 0) mu2[n] = s;
  }
  __syncthreads();
  float4 m4 = *(const float4*)(mulds + 4 * lane);
#pragma unroll
  for (int kk = 0; kk < 2; ++kk) {
    const int k = w * 2 + kk;
    float4 v4 = *(const float4*)(v + ((size_t)n * K_SZ + k) * D_SZ + 4 * lane);
    float s = m4.x * v4.x + m4.y * v4.y + m4.z * v4.z + m4.w * v4.w;
    s = wave_reduce(s);
    if (lane == 0) muv[n * K_SZ + k] = s;
  }
}

__global__ void p1_x2_f(const float* __restrict__ x, float* __restrict__ x2) {
  const int w = threadIdx.x >> 6, lane = threadIdx.x & 63;
  const int b = blockIdx.x * 4 + w;
  float4 t = *(const float4*)(x + (size_t)b * D_SZ + 4 * lane);
  float s = t.x * t.x + t.y * t.y + t.z * t.z + t.w * t.w;
  s = wave_reduce(s);
  if (lane == 0) x2[b] = s;
}

extern "C" void kernel_launch(void* const* d_in, const int* in_sizes, int n_in,
                              void* d_out, int out_size, void* d_ws, size_t ws_size,
                              hipStream_t stream) {
  const float* x   = (const float*)d_in[0];
  const float* mu  = (const float*)d_in[1];
  const float* lam = (const float*)d_in[2];
  const float* v   = (const float*)d_in[3];
  const float* om  = (const float*)d_in[4];
  float* out = (float*)d_out;
  char* wsb = (char*)d_ws;
  float* wsf = (float*)d_ws;
  float* x2  = (float*)(wsb + WS_X2);
  float* mu2 = (float*)(wsb + WS_MU2);
  float* muv = (float*)(wsb + WS_MUV);

  if (ws_size >= WS_NEED) {
    unsigned short* px = (unsigned short*)(wsb + WS_PX);
    unsigned short* pw = (unsigned short*)(wsb + WS_PW);
    const int nunits = B_SZ + N_SZ + N_SZ * K_SZ;   // 74752 waves
    prep_all<<<nunits / 4, 256, 0, stream>>>(x, mu, v, x2, px, mu2, muv, pw);
    hmu_ws<<<1024, 256, 0, stream>>>(px, pw, lam, om, wsf, out);
  } else {
    dim3 grid(N_SZ / NT, B_SZ / BT);
    p1_x2_f<<<B_SZ / 4, 256, 0, stream>>>(x, x2);
    p2_mu_f<<<N_SZ, 256, 0, stream>>>(mu, v, mu2, muv);
    hmu_main_f<<<grid, 256, 0, stream>>>(x, mu, lam, v, om, wsf, out);
  }
}

// Round 10
// 161.650 us; speedup vs baseline: 1.9200x; 1.9200x over previous
//
#include <hip/hip_runtime.h>

// HMULayer omega: out[b][n] = exp(-(lam_n*||x_b-mu_n||^2 + sum_k om_nk*((x_b-mu_n).v_nk)^2)/D)
// B=1024, N=8192, D=256, K=8. 9 fused bf16 MFMA GEMMs sharing A=x.
// R14: R9 geometry (BT=256, rb=4, proven 51.4us) + R8 schedule (counted-vmcnt
//      double-buffer), the one untested {schedule x shape} cell.
//  Model fitting R4-R13: acc144+vgpr~124 = 268 regs -> ONE 4-wave block/CU
//  (occ 17.9%). With a single resident block, __syncthreads' vmcnt(0) drain
//  exposes ~600cyc stage latency serially each kt -> the 33us gap over the
//  18.6us MFMA floor. R8's dbuf was neutral at BT=128 because 2 blocks/CU
//  already overlapped implicitly (m114); at 1 block/CU explicit pipelining is
//  the only overlap available.
//  Schedule per kt: stage(kt+1) -> vmcnt(7|6) [w0 issues 7 glds16, w1-3 6]
//  -> s_barrier -> ds_read+MFMA (setprio1) -> lgkmcnt(0) -> s_barrier.
//  Loads for kt+1 stay in flight across both barriers.

#define B_SZ 1024
#define N_SZ 8192
#define D_SZ 256
#define K_SZ 8

#define BTM 256      // main-kernel b-tile
#define BT 128       // fallback b-tile
#define NT 16

typedef __bf16 bf16x8 __attribute__((ext_vector_type(8)));
typedef float f32x4 __attribute__((ext_vector_type(4)));
typedef unsigned short u16x4 __attribute__((ext_vector_type(4)));
typedef unsigned short u16x8 __attribute__((ext_vector_type(8)));

// ws byte offsets (R4 layout)
#define WS_X2   0u          // f32[1024]
#define WS_MU2  4096u       // f32[8192]
#define WS_MUV  36864u      // f32[65536]
#define WS_PX   299008u     // bf16[1024*256]   (512 KB)
#define WS_PW   823296u     // bf16[8192*9*256] (36 MB)
#define WS_NEED (823296ull + 37748736ull)

__device__ __forceinline__ float wave_reduce(float s) {
#pragma unroll
  for (int off = 32; off > 0; off >>= 1) s += __shfl_down(s, off);
  return s;
}

__device__ __forceinline__ u16x4 cvt4(float4 t) {
  u16x4 r;
  r[0] = __builtin_bit_cast(unsigned short, (__bf16)t.x);
  r[1] = __builtin_bit_cast(unsigned short, (__bf16)t.y);
  r[2] = __builtin_bit_cast(unsigned short, (__bf16)t.z);
  r[3] = __builtin_bit_cast(unsigned short, (__bf16)t.w);
  return r;
}

__device__ __forceinline__ void glds16(const void* g, const void* l) {
  __builtin_amdgcn_global_load_lds(
      (const __attribute__((address_space(1))) void*)g,
      (__attribute__((address_space(3))) void*)l, 16, 0, 0);
}

// ---- prep_all v2: one wave per row. g<1024: x-row. g<9216: mu-row. else v-row.
__global__ void prep_all(const float* __restrict__ x, const float* __restrict__ mu,
                         const float* __restrict__ v,
                         float* __restrict__ x2, unsigned short* __restrict__ px,
                         float* __restrict__ mu2, float* __restrict__ muv,
                         unsigned short* __restrict__ pw) {
  const int w = threadIdx.x >> 6, lane = threadIdx.x & 63;
  const int g = blockIdx.x * 4 + w;
  if (g < B_SZ) {
    const int b = g;
    float4 t = *(const float4*)(x + (size_t)b * D_SZ + 4 * lane);
    *(u16x4*)(px + (size_t)b * D_SZ + 4 * lane) = cvt4(t);
    float s = t.x * t.x + t.y * t.y + t.z * t.z + t.w * t.w;
    s = wave_reduce(s);
    if (lane == 0) x2[b] = s;
  } else if (g < B_SZ + N_SZ) {
    const int n = g - B_SZ;
    float4 m4 = *(const float4*)(mu + (size_t)n * D_SZ + 4 * lane);
    *(u16x4*)(pw + (size_t)n * 9 * D_SZ + 4 * lane) = cvt4(m4);
    float s = m4.x * m4.x + m4.y * m4.y + m4.z * m4.z + m4.w * m4.w;
    s = wave_reduce(s);
    if (lane == 0) mu2[n] = s;
  } else {
    const int idx = g - (B_SZ + N_SZ);
    const int n = idx >> 3, k = idx & 7;
    float4 m4 = *(const float4*)(mu + (size_t)n * D_SZ + 4 * lane);
    float4 v4 = *(const float4*)(v + ((size_t)n * K_SZ + k) * D_SZ + 4 * lane);
    *(u16x4*)(pw + ((size_t)n * 9 + k + 1) * D_SZ + 4 * lane) = cvt4(v4);
    float s = m4.x * v4.x + m4.y * v4.y + m4.z * v4.z + m4.w * v4.w;
    s = wave_reduce(s);
    if (lane == 0) muv[n * K_SZ + k] = s;
  }
}

// stage one K-step tile (linear LDS dest; global SOURCE chunk pre-swizzled:
// physical chunk ch holds logical chunk ch ^ ((row>>1)&3)).
// glds16 issues per wave: w0 = 4A+3B = 7, w1-3 = 4A+2B = 6.
__device__ __forceinline__ void stage_tile(const unsigned short* __restrict__ px,
                                           const unsigned short* __restrict__ pw,
                                           unsigned short* As, unsigned short* Bs,
                                           int b0, int n0, int k0, int w, int lane) {
  const int nl4 = lane >> 2;           // row within 16
  const int ch = lane & 3;             // physical 16B chunk within 64B row
  const int kc = (ch ^ ((nl4 >> 1) & 3)) * 8;  // logical elem offset
#pragma unroll
  for (int t = 0; t < 4; ++t) {        // A: wave w stages rows w*64 .. w*64+63
    int r0 = w * 64 + t * 16;
    glds16(px + (size_t)(b0 + r0 + nl4) * D_SZ + k0 + kc, As + r0 * 32);
  }
#pragma unroll
  for (int t = 0; t < 3; ++t) {        // B: wave w stages j = w, w+4, w+8
    int i = w + 4 * t;                 // wave-uniform guard
    if (i < 9)
      glds16(pw + ((size_t)(n0 + nl4) * 9 + i) * D_SZ + k0 + kc, Bs + i * 16 * 32);
  }
}

// ---- main: BT=256, rb=4, double-buffered counted-vmcnt pipeline ----
__global__ __launch_bounds__(256, 2)
void hmu_main_p(const unsigned short* __restrict__ px,
                const unsigned short* __restrict__ pw,
                const float* __restrict__ lam, const float* __restrict__ om,
                const float* __restrict__ wsf, float* __restrict__ out) {
  __shared__ __align__(16) unsigned short As[2][BTM * 32];      // 2 x 16 KB
  __shared__ __align__(16) unsigned short Bs[2][NT * 9 * 32];   // 2 x 9 KB

  const float* ws_x2 = wsf;                    // WS_X2/4
  const float* ws_mu2 = wsf + 1024;            // WS_MU2/4
  const float* ws_muv = wsf + 9216;            // WS_MUV/4

  const int tid = threadIdx.x;
  const int lane = tid & 63;
  const int w = tid >> 6;
  const int m = lane & 15;
  const int kg = lane >> 4;

  // XCD-chunked decode (R9 proven: FETCH 21MB): bid&7 = xcd, b-tile innermost.
  const int bid = blockIdx.x;
  const int xcd = bid & 7;
  const int idx = bid >> 3;                     // 0..255 within XCD
  const int n0 = (xcd * 64 + (idx >> 2)) * NT;  // n-tile
  const int b0 = (idx & 3) * BTM;               // b-tile

  f32x4 acc[4][9];
#pragma unroll
  for (int rb = 0; rb < 4; ++rb)
#pragma unroll
    for (int j = 0; j < 9; ++j) acc[rb][j] = (f32x4){0.f, 0.f, 0.f, 0.f};

  // read-side swizzle: logical chunk kg of row m lives at phys kg^((m>>1)&3)
  const int sw = (kg ^ ((m >> 1) & 3)) * 8;

  // prologue: stage kt=0 into buffer 0
  stage_tile(px, pw, As[0], Bs[0], b0, n0, 0, w, lane);

#pragma unroll
  for (int kt = 0; kt < 8; ++kt) {
    const int cur = kt & 1;
    if (kt < 7) {
      stage_tile(px, pw, As[cur ^ 1], Bs[cur ^ 1], b0, n0, (kt + 1) * 32, w, lane);
      // wait for stage(kt) only; stage(kt+1)'s loads stay in flight.
      if (w == 0) asm volatile("s_waitcnt vmcnt(7)" ::: "memory");
      else        asm volatile("s_waitcnt vmcnt(6)" ::: "memory");
    } else {
      asm volatile("s_waitcnt vmcnt(0)" ::: "memory");
    }
    __builtin_amdgcn_s_barrier();   // all waves' kt-tile resident in LDS

    const unsigned short* Ac = As[cur];
    const unsigned short* Bc = Bs[cur];
    bf16x8 bfr[9];
#pragma unroll
    for (int j = 0; j < 9; ++j)
      bfr[j] = *(const bf16x8*)&Bc[(j * 16 + m) * 32 + sw];
    __builtin_amdgcn_s_setprio(1);
#pragma unroll
    for (int rb = 0; rb < 4; ++rb) {
      bf16x8 a = *(const bf16x8*)&Ac[((w * 4 + rb) * 16 + m) * 32 + sw];
#pragma unroll
      for (int j = 0; j < 9; ++j)
        acc[rb][j] = __builtin_amdgcn_mfma_f32_16x16x32_bf16(a, bfr[j], acc[rb][j], 0, 0, 0);
    }
    __builtin_amdgcn_s_setprio(0);
    if (kt < 7) {
      // release buf[cur] for iteration kt+1's stage (overwrite hazard)
      asm volatile("s_waitcnt lgkmcnt(0)" ::: "memory");
      __builtin_amdgcn_s_barrier();
    }
  }

  // epilogue: C/D layout col(n)=lane&15, row(b)=kg*4+reg
  const int n = n0 + m;
  const float lam_n = lam[n];
  const float mu2_n = ws_mu2[n];
  float omr[8], muvr[8];
#pragma unroll
  for (int k = 0; k < 8; ++k) {
    omr[k] = om[n * 8 + k];
    muvr[k] = ws_muv[n * 8 + k];
  }
#pragma unroll
  for (int rb = 0; rb < 4; ++rb) {
#pragma unroll
    for (int r = 0; r < 4; ++r) {
      int b = b0 + (w * 4 + rb) * 16 + kg * 4 + r;
      float x2b = ws_x2[b];
      float c0 = acc[rb][0][r];
      float q = lam_n * (x2b - 2.f * c0 + mu2_n);
#pragma unroll
      for (int k = 0; k < 8; ++k) {
        float p = acc[rb][k + 1][r] - muvr[k];
        q = fmaf(omr[k] * p, p, q);
      }
      out[(size_t)b * N_SZ + n] = __expf(q * (-1.0f / 256.0f));
    }
  }
}

// ================= fallback path (R2): in-loop cvt staging =================
__device__ __forceinline__ void cvt16_store(const float* __restrict__ src,
                                            unsigned short* dst) {
  const float4* p4 = (const float4*)src;
  float fv[16];
#pragma unroll
  for (int e = 0; e < 4; ++e) {
    float4 t = p4[e];
    fv[4 * e + 0] = t.x; fv[4 * e + 1] = t.y;
    fv[4 * e + 2] = t.z; fv[4 * e + 3] = t.w;
  }
  u16x8 lo, hi;
#pragma unroll
  for (int e = 0; e < 8; ++e) {
    lo[e] = __builtin_bit_cast(unsigned short, (__bf16)fv[e]);
    hi[e] = __builtin_bit_cast(unsigned short, (__bf16)fv[e + 8]);
  }
  *(u16x8*)dst = lo;
  *(u16x8*)(dst + 8) = hi;
}

#define LDS_STRIDE 40
__global__ __launch_bounds__(256, 2)
void hmu_main_f(const float* __restrict__ x, const float* __restrict__ mu,
                const float* __restrict__ lam, const float* __restrict__ v,
                const float* __restrict__ om, const float* __restrict__ ws,
                float* __restrict__ out) {
  __shared__ __align__(16) unsigned short As[BT * LDS_STRIDE];
  __shared__ __align__(16) unsigned short Bs[NT * 9 * LDS_STRIDE];
  const float* ws_x2 = ws;
  const float* ws_mu2 = ws + 1024;
  const float* ws_muv = ws + 9216;
  const int tid = threadIdx.x, lane = tid & 63, w = tid >> 6;
  const int m = lane & 15, kg = lane >> 4;
  const int n0 = blockIdx.x * NT, b0 = blockIdx.y * BT;
  f32x4 acc[2][9];
#pragma unroll
  for (int bs = 0; bs < 2; ++bs)
#pragma unroll
    for (int j = 0; j < 9; ++j) acc[bs][j] = (f32x4){0.f, 0.f, 0.f, 0.f};
  const int arow = tid >> 1, ahalf = tid & 1;
  for (int kt = 0; kt < 8; ++kt) {
    const int k0 = kt * 32;
    cvt16_store(x + (size_t)(b0 + arow) * D_SZ + k0 + ahalf * 16,
                &As[arow * LDS_STRIDE + ahalf * 16]);
#pragma unroll
    for (int it = 0; it < 2; ++it) {
      int idx = tid + 256 * it;
      if (idx < 288) {
        int row = idx >> 1, half = idx & 1;
        int nl = row / 9, j = row - nl * 9;
        const float* src = (j == 0)
            ? mu + (size_t)(n0 + nl) * D_SZ + k0 + half * 16
            : v + (size_t)((n0 + nl) * K_SZ + (j - 1)) * D_SZ + k0 + half * 16;
        cvt16_store(src, &Bs[row * LDS_STRIDE + half * 16]);
      }
    }
    __syncthreads();
    bf16x8 af[2];
#pragma unroll
    for (int bs = 0; bs < 2; ++bs)
      af[bs] = *(const bf16x8*)&As[((2 * w + bs) * 16 + m) * LDS_STRIDE + kg * 8];
#pragma unroll
    for (int j = 0; j < 9; ++j) {
      bf16x8 bfr = *(const bf16x8*)&Bs[(m * 9 + j) * LDS_STRIDE + kg * 8];
      acc[0][j] = __builtin_amdgcn_mfma_f32_16x16x32_bf16(af[0], bfr, acc[0][j], 0, 0, 0);
      acc[1][j] = __builtin_amdgcn_mfma_f32_16x16x32_bf16(af[1], bfr, acc[1][j], 0, 0, 0);
    }
    __syncthreads();
  }
  const int n = n0 + m;
  const float lam_n = lam[n];
  const float mu2_n = ws_mu2[n];
  float omr[8], muvr[8];
#pragma unroll
  for (int k = 0; k < 8; ++k) {
    omr[k] = om[n * 8 + k];
    muvr[k] = ws_muv[n * 8 + k];
  }
#pragma unroll
  for (int bs = 0; bs < 2; ++bs)
#pragma unroll
    for (int r = 0; r < 4; ++r) {
      int b = b0 + (2 * w + bs) * 16 + kg * 4 + r;
      float c0 = acc[bs][0][r];
      float q = lam_n * (ws_x2[b] - 2.f * c0 + mu2_n);
#pragma unroll
      for (int k = 0; k < 8; ++k) {
        float p = acc[bs][k + 1][r] - muvr[k];
        q = fmaf(omr[k] * p, p, q);
      }
      out[(size_t)b * N_SZ + n] = __expf(q * (-1.0f / 256.0f));
    }
}

__global__ void p2_mu_f(const float* __restrict__ mu, const float* __restrict__ v,
                        float* __restrict__ mu2, float* __restrict__ muv) {
  __shared__ __align__(16) float mulds[D_SZ];
  const int n = blockIdx.x;
  const int w = threadIdx.x >> 6, lane = threadIdx.x & 63;
  if (w == 0) {
    float4 m4 = *(const float4*)(mu + (size_t)n * D_SZ + 4 * lane);
    *(float4*)(mulds + 4 * lane) = m4;
    float s = m4.x * m4.x + m4.y * m4.y + m4.z * m4.z + m4.w * m4.w;
    s = wave_reduce(s);
    if (lane == 0) mu2[n] = s;
  }
  __syncthreads();
  float4 m4 = *(const float4*)(mulds + 4 * lane);
#pragma unroll
  for (int kk = 0; kk < 2; ++kk) {
    const int k = w * 2 + kk;
    float4 v4 = *(const float4*)(v + ((size_t)n * K_SZ + k) * D_SZ + 4 * lane);
    float s = m4.x * v4.x + m4.y * v4.y + m4.z * v4.z + m4.w * v4.w;
    s = wave_reduce(s);
    if (lane == 0) muv[n * K_SZ + k] = s;
  }
}

__global__ void p1_x2_f(const float* __restrict__ x, float* __restrict__ x2) {
  const int w = threadIdx.x >> 6, lane = threadIdx.x & 63;
  const int b = blockIdx.x * 4 + w;
  float4 t = *(const float4*)(x + (size_t)b * D_SZ + 4 * lane);
  float s = t.x * t.x + t.y * t.y + t.z * t.z + t.w * t.w;
  s = wave_reduce(s);
  if (lane == 0) x2[b] = s;
}

extern "C" void kernel_launch(void* const* d_in, const int* in_sizes, int n_in,
                              void* d_out, int out_size, void* d_ws, size_t ws_size,
                              hipStream_t stream) {
  const float* x   = (const float*)d_in[0];
  const float* mu  = (const float*)d_in[1];
  const float* lam = (const float*)d_in[2];
  const float* v   = (const float*)d_in[3];
  const float* om  = (const float*)d_in[4];
  float* out = (float*)d_out;
  char* wsb = (char*)d_ws;
  float* wsf = (float*)d_ws;
  float* x2  = (float*)(wsb + WS_X2);
  float* mu2 = (float*)(wsb + WS_MU2);
  float* muv = (float*)(wsb + WS_MUV);

  if (ws_size >= WS_NEED) {
    unsigned short* px = (unsigned short*)(wsb + WS_PX);
    unsigned short* pw = (unsigned short*)(wsb + WS_PW);
    const int nunits = B_SZ + N_SZ + N_SZ * K_SZ;   // 74752 waves
    prep_all<<<nunits / 4, 256, 0, stream>>>(x, mu, v, x2, px, mu2, muv, pw);
    hmu_main_p<<<(N_SZ / NT) * (B_SZ / BTM), 256, 0, stream>>>(px, pw, lam, om, wsf, out);
  } else {
    dim3 grid(N_SZ / NT, B_SZ / BT);
    p1_x2_f<<<B_SZ / 4, 256, 0, stream>>>(x, x2);
    p2_mu_f<<<N_SZ, 256, 0, stream>>>(mu, v, mu2, muv);
    hmu_main_f<<<grid, 256, 0, stream>>>(x, mu, lam, v, om, wsf, out);
  }
}